// Round 1
// baseline (766.516 us; speedup 1.0000x reference)
//
#include <hip/hip_runtime.h>
#include <hip/hip_bf16.h>
#include <math.h>

#define NTOK 1024
#define DIN  512
#define NF   4
#define DCOND 128
#define H    8
#define HD   64
#define NQKV 1536
#define ROWS 8

// ---------------- prep: code_mod for qkv and proj ----------------
__global__ void prep_kernel(const float* __restrict__ code,
                            const float* __restrict__ w_c,
                            const float* __restrict__ lnqg, const float* __restrict__ lnqb,
                            const float* __restrict__ lnpg, const float* __restrict__ lnpb,
                            float* __restrict__ cmq, float* __restrict__ cmp_) {
  int i = threadIdx.x;  // 0..511
  float t[NF] = {0.f, 0.f, 0.f, 0.f};
  for (int k = 0; k < DCOND; ++k) {
    float w = w_c[i * DCOND + k];
    float4 cd = *reinterpret_cast<const float4*>(&code[k * NF]);
    t[0] += w * cd.x; t[1] += w * cd.y; t[2] += w * cd.z; t[3] += w * cd.w;
  }
  __shared__ float buf[512];
  for (int f = 0; f < NF; ++f) {
    buf[i] = t[f]; __syncthreads();
    for (int s = 256; s > 0; s >>= 1) { if (i < s) buf[i] += buf[i + s]; __syncthreads(); }
    float mu = buf[0] * (1.f / 512.f); __syncthreads();
    float d = t[f] - mu;
    buf[i] = d * d; __syncthreads();
    for (int s = 256; s > 0; s >>= 1) { if (i < s) buf[i] += buf[i + s]; __syncthreads(); }
    float rstd = rsqrtf(buf[0] * (1.f / 512.f) + 1e-5f);
    float nv = d * rstd;
    cmq[f * DIN + i]  = nv * lnqg[i] + lnqb[i];
    cmp_[f * DIN + i] = nv * lnpg[i] + lnpb[i];
    __syncthreads();
  }
}

// ---------------- modlin GEMM: out[f,n,c] = (A[f?][n,:]*cm[f,:]) @ W[c,:] + bias[c] ----------------
__global__ __launch_bounds__(256)
void modlin_gemm(const float* __restrict__ A, long aFStride,
                 const float* __restrict__ cm,
                 const float* __restrict__ W,
                 const float* __restrict__ bias,
                 float* __restrict__ out, int Ncol) {
  const int f = blockIdx.z;
  const float* Af = A + (long)f * aFStride;
  const int row0 = blockIdx.y * 64, col0 = blockIdx.x * 64;
  __shared__ __align__(16) float sA[16][68];
  __shared__ __align__(16) float sB[16][68];
  const int tid = threadIdx.x;
  const int ty = tid >> 4, tx = tid & 15;
  const int lm = tid >> 2;          // 0..63 (row within tile)
  const int lk = (tid & 3) * 4;     // 0,4,8,12
  const float* cmf = cm + f * DIN;
  float acc[4][4] = {};
  for (int k0 = 0; k0 < DIN; k0 += 16) {
    float4 av = *reinterpret_cast<const float4*>(&Af[(long)(row0 + lm) * DIN + k0 + lk]);
    float4 cv = *reinterpret_cast<const float4*>(&cmf[k0 + lk]);
    av.x *= cv.x; av.y *= cv.y; av.z *= cv.z; av.w *= cv.w;
    float4 bv = *reinterpret_cast<const float4*>(&W[(long)(col0 + lm) * DIN + k0 + lk]);
    sA[lk + 0][lm] = av.x; sA[lk + 1][lm] = av.y; sA[lk + 2][lm] = av.z; sA[lk + 3][lm] = av.w;
    sB[lk + 0][lm] = bv.x; sB[lk + 1][lm] = bv.y; sB[lk + 2][lm] = bv.z; sB[lk + 3][lm] = bv.w;
    __syncthreads();
#pragma unroll
    for (int kk = 0; kk < 16; ++kk) {
      float4 a4 = *reinterpret_cast<const float4*>(&sA[kk][ty * 4]);
      float4 b4 = *reinterpret_cast<const float4*>(&sB[kk][tx * 4]);
      float a[4] = {a4.x, a4.y, a4.z, a4.w};
      float b[4] = {b4.x, b4.y, b4.z, b4.w};
#pragma unroll
      for (int i2 = 0; i2 < 4; ++i2)
#pragma unroll
        for (int j = 0; j < 4; ++j) acc[i2][j] += a[i2] * b[j];
    }
    __syncthreads();
  }
  const float4 bb = *reinterpret_cast<const float4*>(&bias[col0 + tx * 4]);
#pragma unroll
  for (int i2 = 0; i2 < 4; ++i2) {
    int r = row0 + ty * 4 + i2;
    float4 o;
    o.x = acc[i2][0] + bb.x; o.y = acc[i2][1] + bb.y;
    o.z = acc[i2][2] + bb.z; o.w = acc[i2][3] + bb.w;
    *reinterpret_cast<float4*>(&out[((long)(f * NTOK + r)) * Ncol + col0 + tx * 4]) = o;
  }
}

// ---------------- attention with double softmax + compat ----------------
__global__ __launch_bounds__(256)
void attn_kernel(const float* __restrict__ qkv,
                 const float* __restrict__ comp,
                 float* __restrict__ yhat) {
  const int bx = blockIdx.x;            // row tile 0..127
  const int h = blockIdx.y >> 2;        // 0..7
  const int f = blockIdx.y & 3;         // 0..3
  const int r0 = bx * ROWS;
  const int tid = threadIdx.x;
  const int lane = tid & 63;
  const int w = tid >> 6;               // wave 0..3, owns rows 2w, 2w+1

  __shared__ float S[ROWS][NTOK];       // 32 KB score rows
  __shared__ float ks[64][65];          // k/v tile, padded
  __shared__ float qs[ROWS][HD];
  __shared__ float crow[NF][ROWS];

  const float* qb = qkv + ((long)(f * NTOK)) * NQKV + h * HD;
  const float* kb = qb + DIN;
  const float* vb = qb + 2 * DIN;

  for (int idx = tid; idx < ROWS * HD; idx += 256) {
    int r = idx >> 6, d = idx & 63;
    qs[r][d] = qb[(long)(r0 + r) * NQKV + d];
  }
  if (tid < NF * ROWS) {
    int ff = tid >> 3, r = tid & 7;
    crow[ff][r] = comp[ff * NTOK + r0 + r];
  }

  const float scale = 0.125f;  // 64^-0.5
  // ---- phase 1: S = scale * q k^T ----
  for (int mt = 0; mt < NTOK / 64; ++mt) {
    __syncthreads();
#pragma unroll
    for (int p = 0; p < 4; ++p) {
      int c = (tid >> 4) + p * 16;
      int dd = (tid & 15) * 4;
      float4 kv = *reinterpret_cast<const float4*>(&kb[(long)(mt * 64 + c) * NQKV + dd]);
      ks[c][dd] = kv.x; ks[c][dd + 1] = kv.y; ks[c][dd + 2] = kv.z; ks[c][dd + 3] = kv.w;
    }
    __syncthreads();
    const int r = 2 * w;
    float acc0 = 0.f, acc1 = 0.f;
#pragma unroll
    for (int d = 0; d < HD; ++d) {
      float kv = ks[lane][d];
      acc0 += qs[r][d] * kv;
      acc1 += qs[r + 1][d] * kv;
    }
    S[r][mt * 64 + lane] = acc0 * scale;
    S[r + 1][mt * 64 + lane] = acc1 * scale;
  }

  // ---- phase 2: softmax -> *compat -> softmax (wave-local rows) ----
  const float* cp0 = comp;
  const float* cp1 = comp + NTOK;
  const float* cp2 = comp + 2 * NTOK;
  const float* cp3 = comp + 3 * NTOK;
#pragma unroll
  for (int rr = 0; rr < 2; ++rr) {
    const int r = 2 * w + rr;
    float* Srow = S[r];
    const float q0 = crow[0][r], q1 = crow[1][r], q2 = crow[2][r], q3 = crow[3][r];
    float pm = -1e30f;
    for (int i2 = 0; i2 < 16; ++i2) pm = fmaxf(pm, Srow[lane + 64 * i2]);
#pragma unroll
    for (int off = 32; off > 0; off >>= 1) pm = fmaxf(pm, __shfl_xor(pm, off));
    float ps = 0.f;
    for (int i2 = 0; i2 < 16; ++i2) ps += expf(Srow[lane + 64 * i2] - pm);
#pragma unroll
    for (int off = 32; off > 0; off >>= 1) ps += __shfl_xor(ps, off);
    const float invl = 1.f / ps;
    float wm = -1e30f;
    for (int i2 = 0; i2 < 16; ++i2) {
      int m = lane + 64 * i2;
      float a = expf(Srow[m] - pm) * invl;
      float cc = q0 * cp0[m] + q1 * cp1[m] + q2 * cp2[m] + q3 * cp3[m];
      float whv = a * cc;
      Srow[m] = whv;
      wm = fmaxf(wm, whv);
    }
#pragma unroll
    for (int off = 32; off > 0; off >>= 1) wm = fmaxf(wm, __shfl_xor(wm, off));
    float wsum = 0.f;
    for (int i2 = 0; i2 < 16; ++i2) wsum += expf(Srow[lane + 64 * i2] - wm);
#pragma unroll
    for (int off = 32; off > 0; off >>= 1) wsum += __shfl_xor(wsum, off);
    const float invL = 1.f / wsum;
    for (int i2 = 0; i2 < 16; ++i2) {
      int m = lane + 64 * i2;
      Srow[m] = expf(Srow[m] - wm) * invL;
    }
  }

  // ---- phase 3: PV ----
  float o0 = 0.f, o1 = 0.f;
  const int d = lane;
  const int r = 2 * w;
  for (int mt = 0; mt < NTOK / 64; ++mt) {
    __syncthreads();
#pragma unroll
    for (int p = 0; p < 4; ++p) {
      int c = (tid >> 4) + p * 16;
      int dd = (tid & 15) * 4;
      float4 vv = *reinterpret_cast<const float4*>(&vb[(long)(mt * 64 + c) * NQKV + dd]);
      ks[c][dd] = vv.x; ks[c][dd + 1] = vv.y; ks[c][dd + 2] = vv.z; ks[c][dd + 3] = vv.w;
    }
    __syncthreads();
#pragma unroll
    for (int m = 0; m < 64; ++m) {
      float vv = ks[m][d];
      o0 += S[r][mt * 64 + m] * vv;
      o1 += S[r + 1][mt * 64 + m] * vv;
    }
  }
  yhat[((long)(f * NTOK) + r0 + r) * DIN + h * HD + d] = o0;
  yhat[((long)(f * NTOK) + r0 + r + 1) * DIN + h * HD + d] = o1;
}

extern "C" void kernel_launch(void* const* d_in, const int* in_sizes, int n_in,
                              void* d_out, int out_size, void* d_ws, size_t ws_size,
                              hipStream_t stream) {
  const float* x      = (const float*)d_in[0];
  const float* compat = (const float*)d_in[1];
  const float* code   = (const float*)d_in[2];
  const float* w_c    = (const float*)d_in[3];
  const float* W_qkv  = (const float*)d_in[4];
  const float* b_qkv  = (const float*)d_in[5];
  const float* W_proj = (const float*)d_in[6];
  const float* b_proj = (const float*)d_in[7];
  const float* lnqg   = (const float*)d_in[8];
  const float* lnqb   = (const float*)d_in[9];
  const float* lnpg   = (const float*)d_in[10];
  const float* lnpb   = (const float*)d_in[11];
  float* out = (float*)d_out;

  float* ws   = (float*)d_ws;
  float* cmq  = ws;                            // [4][512]
  float* cmp_ = cmq + NF * DIN;                // [4][512]
  float* qkv  = cmp_ + NF * DIN;               // [4][1024][1536]
  float* yhat = qkv + (long)NF * NTOK * NQKV;  // [4][1024][512]

  prep_kernel<<<1, 512, 0, stream>>>(code, w_c, lnqg, lnqb, lnpg, lnpb, cmq, cmp_);
  modlin_gemm<<<dim3(NQKV / 64, NTOK / 64, NF), 256, 0, stream>>>(
      x, 0L, cmq, W_qkv, b_qkv, qkv, NQKV);
  attn_kernel<<<dim3(NTOK / ROWS, H * NF), 256, 0, stream>>>(qkv, compat, yhat);
  modlin_gemm<<<dim3(DIN / 64, NTOK / 64, NF), 256, 0, stream>>>(
      yhat, (long)NTOK * DIN, cmp_, W_proj, b_proj, out, DIN);
}

// Round 3
// 192.746 us; speedup vs baseline: 3.9768x; 3.9768x over previous
//
#include <hip/hip_runtime.h>
#include <hip/hip_bf16.h>
#include <math.h>

#define NTOK 1024
#define DIN  512
#define NF   4
#define DCOND 128
#define H    8
#define HD   64
#define NQKV 1536

typedef __attribute__((ext_vector_type(8))) short bf16x8;
typedef __attribute__((ext_vector_type(4))) float f32x4;
typedef __attribute__((ext_vector_type(4))) unsigned short us4;

__device__ __forceinline__ unsigned short f2b(float f) {
  union { float f; unsigned int u; } v; v.f = f;
  unsigned int r = v.u + 0x7fffu + ((v.u >> 16) & 1u);
  return (unsigned short)(r >> 16);
}

__device__ __forceinline__ float b2f(unsigned short h) {
  union { unsigned int u; float f; } v; v.u = ((unsigned int)h) << 16;
  return v.f;
}

__device__ __forceinline__ void gl_lds16(const void* g, void* l) {
  __builtin_amdgcn_global_load_lds(
      (const __attribute__((address_space(1))) unsigned int*)g,
      (__attribute__((address_space(3))) unsigned int*)l, 16, 0, 0);
}

// ---------------- prep (block 0: code_mod LN) + weight f32->bf16 convert ----------------
__global__ void prep_convert(const float* __restrict__ code, const float* __restrict__ w_c,
                             const float* __restrict__ lnqg, const float* __restrict__ lnqb,
                             const float* __restrict__ lnpg, const float* __restrict__ lnpb,
                             const float* __restrict__ W_qkv, const float* __restrict__ W_proj,
                             float* __restrict__ cmq, float* __restrict__ cmp_,
                             unsigned short* __restrict__ Wqh, unsigned short* __restrict__ Wph) {
  if (blockIdx.x == 0) {
    int i = threadIdx.x;  // 0..511
    float t[NF] = {0.f, 0.f, 0.f, 0.f};
    for (int k = 0; k < DCOND; ++k) {
      float w = w_c[i * DCOND + k];
      float4 cd = *reinterpret_cast<const float4*>(&code[k * NF]);
      t[0] += w * cd.x; t[1] += w * cd.y; t[2] += w * cd.z; t[3] += w * cd.w;
    }
    __shared__ float buf[512];
    for (int f = 0; f < NF; ++f) {
      buf[i] = t[f]; __syncthreads();
      for (int s = 256; s > 0; s >>= 1) { if (i < s) buf[i] += buf[i + s]; __syncthreads(); }
      float mu = buf[0] * (1.f / 512.f); __syncthreads();
      float d = t[f] - mu;
      buf[i] = d * d; __syncthreads();
      for (int s = 256; s > 0; s >>= 1) { if (i < s) buf[i] += buf[i + s]; __syncthreads(); }
      float rstd = rsqrtf(buf[0] * (1.f / 512.f) + 1e-5f);
      float nv = d * rstd;
      cmq[f * DIN + i]  = nv * lnqg[i] + lnqb[i];
      cmp_[f * DIN + i] = nv * lnpg[i] + lnpb[i];
      __syncthreads();
    }
  } else {
    int e0 = ((blockIdx.x - 1) * 512 + threadIdx.x) * 8;  // 0..1048568
    const float* src; unsigned short* dst; int e;
    if (e0 < 786432) { src = W_qkv; dst = Wqh; e = e0; }
    else { src = W_proj; dst = Wph; e = e0 - 786432; }
    float4 a = *reinterpret_cast<const float4*>(&src[e]);
    float4 b = *reinterpret_cast<const float4*>(&src[e + 4]);
    us4 p0 = { f2b(a.x), f2b(a.y), f2b(a.z), f2b(a.w) };
    us4 p1 = { f2b(b.x), f2b(b.y), f2b(b.z), f2b(b.w) };
    *reinterpret_cast<us4*>(&dst[e]) = p0;
    *reinterpret_cast<us4*>(&dst[e + 4]) = p1;
  }
}

// ---------------- modulated GEMM: out[row, c] = (A[row,:]*cm[f,:]) @ Wh[c,:] + bias[c] ----------------
// rows fold f: row in [0,4096), f = row>>10. A row index = row & aMask (1023 broadcasts x).
template<int NCOL, bool OUT_BF16, bool WRITE_VT>
__global__ __launch_bounds__(256, 2)
void gemm_mod(const float* __restrict__ Asrc, int aMask,
              const float* __restrict__ cm,
              const unsigned short* __restrict__ Wh,
              const float* __restrict__ bias,
              unsigned short* __restrict__ outH,
              float* __restrict__ outF,
              unsigned short* __restrict__ vT) {
  __shared__ __align__(16) unsigned short sA[128 * 40];  // padded stride 40
  __shared__ __align__(16) unsigned short sB[128 * 32];  // linear, XOR-swizzled via source
  const int tid = threadIdx.x;
  const int lane = tid & 63, w = tid >> 6;
  const int li = lane & 15, g = lane >> 4;
  const int wr = (w >> 1) * 64, wc = (w & 1) * 64;
  const int row0 = blockIdx.y * 128, col0 = blockIdx.x * 128;
  const int f = row0 >> 10;
  const int sr = tid >> 1, skh = (tid & 1) * 16;
  const float* aRow = Asrc + (size_t)((row0 + sr) & aMask) * DIN + skh;
  const float* cmRow = cm + f * DIN + skh;

  f32x4 acc[4][4];
#pragma unroll
  for (int m = 0; m < 4; ++m)
#pragma unroll
    for (int n = 0; n < 4; ++n) acc[m][n] = (f32x4){0.f, 0.f, 0.f, 0.f};

  for (int k0 = 0; k0 < DIN; k0 += 32) {
    // A stage: f32 * cm -> bf16, padded LDS
    float4 x0 = *reinterpret_cast<const float4*>(aRow + k0);
    float4 x1 = *reinterpret_cast<const float4*>(aRow + k0 + 4);
    float4 x2 = *reinterpret_cast<const float4*>(aRow + k0 + 8);
    float4 x3 = *reinterpret_cast<const float4*>(aRow + k0 + 12);
    float4 c0 = *reinterpret_cast<const float4*>(cmRow + k0);
    float4 c1 = *reinterpret_cast<const float4*>(cmRow + k0 + 4);
    float4 c2 = *reinterpret_cast<const float4*>(cmRow + k0 + 8);
    float4 c3 = *reinterpret_cast<const float4*>(cmRow + k0 + 12);
    bf16x8 p0, p1;
    p0[0] = (short)f2b(x0.x * c0.x); p0[1] = (short)f2b(x0.y * c0.y);
    p0[2] = (short)f2b(x0.z * c0.z); p0[3] = (short)f2b(x0.w * c0.w);
    p0[4] = (short)f2b(x1.x * c1.x); p0[5] = (short)f2b(x1.y * c1.y);
    p0[6] = (short)f2b(x1.z * c1.z); p0[7] = (short)f2b(x1.w * c1.w);
    p1[0] = (short)f2b(x2.x * c2.x); p1[1] = (short)f2b(x2.y * c2.y);
    p1[2] = (short)f2b(x2.z * c2.z); p1[3] = (short)f2b(x2.w * c2.w);
    p1[4] = (short)f2b(x3.x * c3.x); p1[5] = (short)f2b(x3.y * c3.y);
    p1[6] = (short)f2b(x3.z * c3.z); p1[7] = (short)f2b(x3.w * c3.w);
    *reinterpret_cast<bf16x8*>(&sA[sr * 40 + skh]) = p0;
    *reinterpret_cast<bf16x8*>(&sA[sr * 40 + skh + 8]) = p1;
    // B stage: global_load_lds, source pre-swizzled
#pragma unroll
    for (int j = 0; j < 2; ++j) {
      int slot = w * 128 + j * 64 + lane;
      int bcol = slot >> 2, sp = slot & 3;
      int s = sp ^ ((bcol >> 1) & 3);
      gl_lds16(Wh + (size_t)(col0 + bcol) * DIN + k0 + s * 8, &sB[(w * 128 + j * 64) * 8]);
    }
    __syncthreads();
    bf16x8 aF[4], bF[4];
#pragma unroll
    for (int m = 0; m < 4; ++m)
      aF[m] = *reinterpret_cast<const bf16x8*>(&sA[(wr + m * 16 + li) * 40 + g * 8]);
#pragma unroll
    for (int n = 0; n < 4; ++n) {
      int bcol = wc + n * 16 + li;
      int slot = bcol * 4 + (g ^ ((bcol >> 1) & 3));
      bF[n] = *reinterpret_cast<const bf16x8*>(&sB[slot * 8]);
    }
#pragma unroll
    for (int m = 0; m < 4; ++m)
#pragma unroll
      for (int n = 0; n < 4; ++n)
        acc[m][n] = __builtin_amdgcn_mfma_f32_16x16x32_bf16(aF[m], bF[n], acc[m][n], 0, 0, 0);
    __syncthreads();
  }
  // epilogue
#pragma unroll
  for (int n = 0; n < 4; ++n) {
    int col = col0 + wc + n * 16 + li;
    float bb = bias[col];
#pragma unroll
    for (int m = 0; m < 4; ++m) {
      int rb = row0 + wr + m * 16 + g * 4;
      f32x4 v = acc[m][n];
      if constexpr (OUT_BF16) {
        if (WRITE_VT && col >= 1024) {
          int tok0 = rb & 1023;  // within-f token (BUGFIX: was global row)
          us4 pk;
#pragma unroll
          for (int r = 0; r < 4; ++r) pk[r] = f2b(v[r] + bb);
          *reinterpret_cast<us4*>(&vT[((size_t)(f * 512 + (col - 1024))) * NTOK + tok0]) = pk;
        } else {
#pragma unroll
          for (int r = 0; r < 4; ++r)
            outH[(size_t)(rb + r) * NCOL + col] = f2b(v[r] + bb);
        }
      } else {
#pragma unroll
        for (int r = 0; r < 4; ++r)
          outF[(size_t)(rb + r) * NCOL + col] = v[r] + bb;
      }
    }
  }
}

// ---------------- MFMA attention with double softmax (two-pass flash) ----------------
__global__ __launch_bounds__(256, 2)
void attn_mfma(const unsigned short* __restrict__ qkvh,  // [4][1024][1536] bf16
               const unsigned short* __restrict__ vTh,   // [4][512][1024] bf16 (V^T)
               const float* __restrict__ comp,           // [4][1024]
               float* __restrict__ yhat) {               // [4][1024][512] f32
  __shared__ __align__(16) unsigned short sK[64 * 64];
  __shared__ __align__(16) unsigned short sVT[64 * 64];
  __shared__ __align__(16) unsigned short sW[4][16 * 72];  // per-wave, padded
  __shared__ float scomp[4096];
  const int tid = threadIdx.x, lane = tid & 63, w = tid >> 6;
  const int li = lane & 15, g = lane >> 4;
  const int qt = blockIdx.x;
  const int h = blockIdx.y >> 2, f = blockIdx.y & 3;

  for (int i = tid * 4; i < 4096; i += 1024)
    *reinterpret_cast<float4*>(&scomp[i]) = *reinterpret_cast<const float4*>(&comp[i]);

  const int qrow0 = qt * 64 + w * 16;
  const unsigned short* qbase = qkvh + ((size_t)(f * NTOK + qrow0 + li)) * NQKV + h * HD;
  bf16x8 aq[2];
  aq[0] = *reinterpret_cast<const bf16x8*>(qbase + g * 8);
  aq[1] = *reinterpret_cast<const bf16x8*>(qbase + 32 + g * 8);

  float crow[4][4];
#pragma unroll
  for (int ff = 0; ff < 4; ++ff)
#pragma unroll
    for (int r = 0; r < 4; ++r)
      crow[ff][r] = comp[ff * NTOK + qrow0 + g * 4 + r];

  const unsigned short* kb = qkvh + ((size_t)(f * NTOK)) * NQKV + DIN + h * HD;
  const unsigned short* vb = vTh + ((size_t)(f * DIN + h * HD)) * NTOK;

  float mrow[4], lrow[4];
#pragma unroll
  for (int r = 0; r < 4; ++r) { mrow[r] = -1e30f; lrow[r] = 0.f; }

  // ---- pass A: softmax-1 stats ----
  for (int t = 0; t < 16; ++t) {
    __syncthreads();
#pragma unroll
    for (int j = 0; j < 2; ++j) {
      int slot = w * 128 + j * 64 + lane;
      int tok = slot >> 3, sp = slot & 7, s = sp ^ (tok & 7);
      gl_lds16(kb + (size_t)(t * 64 + tok) * NQKV + s * 8, &sK[(w * 128 + j * 64) * 8]);
    }
    __syncthreads();
    bf16x8 bk[4][2];
#pragma unroll
    for (int cf = 0; cf < 4; ++cf)
#pragma unroll
      for (int ks = 0; ks < 2; ++ks) {
        int tok = cf * 16 + li, s = ks * 4 + g;
        bk[cf][ks] = *reinterpret_cast<const bf16x8*>(&sK[(tok * 8 + (s ^ (tok & 7))) * 8]);
      }
    f32x4 accs[4];
#pragma unroll
    for (int cf = 0; cf < 4; ++cf) accs[cf] = (f32x4){0.f, 0.f, 0.f, 0.f};
#pragma unroll
    for (int ks = 0; ks < 2; ++ks)
#pragma unroll
      for (int cf = 0; cf < 4; ++cf)
        accs[cf] = __builtin_amdgcn_mfma_f32_16x16x32_bf16(aq[ks], bk[cf][ks], accs[cf], 0, 0, 0);
#pragma unroll
    for (int r = 0; r < 4; ++r) {
      float v0 = accs[0][r] * 0.125f, v1 = accs[1][r] * 0.125f;
      float v2 = accs[2][r] * 0.125f, v3 = accs[3][r] * 0.125f;
      float tm = fmaxf(fmaxf(v0, v1), fmaxf(v2, v3));
#pragma unroll
      for (int o = 8; o > 0; o >>= 1) tm = fmaxf(tm, __shfl_xor(tm, o));
      float nm = fmaxf(mrow[r], tm);
      float ssum = __expf(v0 - nm) + __expf(v1 - nm) + __expf(v2 - nm) + __expf(v3 - nm);
#pragma unroll
      for (int o = 8; o > 0; o >>= 1) ssum += __shfl_xor(ssum, o);
      lrow[r] = lrow[r] * __expf(mrow[r] - nm) + ssum;
      mrow[r] = nm;
    }
  }
  float inv_l[4];
#pragma unroll
  for (int r = 0; r < 4; ++r) inv_l[r] = 1.f / lrow[r];

  // ---- pass B: recompute S, t=exp(attn*cc), PV + sum2 ----
  f32x4 acco[4];
  float sum2[4] = {0.f, 0.f, 0.f, 0.f};
#pragma unroll
  for (int cf = 0; cf < 4; ++cf) acco[cf] = (f32x4){0.f, 0.f, 0.f, 0.f};
  unsigned short* wbuf = &sW[w][0];

  for (int t = 0; t < 16; ++t) {
    __syncthreads();
#pragma unroll
    for (int j = 0; j < 2; ++j) {
      int slot = w * 128 + j * 64 + lane;
      int tok = slot >> 3, sp = slot & 7, s = sp ^ (tok & 7);
      gl_lds16(kb + (size_t)(t * 64 + tok) * NQKV + s * 8, &sK[(w * 128 + j * 64) * 8]);
    }
#pragma unroll
    for (int j = 0; j < 2; ++j) {
      int slot = w * 128 + j * 64 + lane;
      int d = slot >> 3, sp = slot & 7, s = sp ^ (d & 7);
      gl_lds16(vb + (size_t)d * NTOK + t * 64 + s * 8, &sVT[(w * 128 + j * 64) * 8]);
    }
    __syncthreads();
    bf16x8 bk[4][2];
#pragma unroll
    for (int cf = 0; cf < 4; ++cf)
#pragma unroll
      for (int ks = 0; ks < 2; ++ks) {
        int tok = cf * 16 + li, s = ks * 4 + g;
        bk[cf][ks] = *reinterpret_cast<const bf16x8*>(&sK[(tok * 8 + (s ^ (tok & 7))) * 8]);
      }
    f32x4 accs[4];
#pragma unroll
    for (int cf = 0; cf < 4; ++cf) accs[cf] = (f32x4){0.f, 0.f, 0.f, 0.f};
#pragma unroll
    for (int ks = 0; ks < 2; ++ks)
#pragma unroll
      for (int cf = 0; cf < 4; ++cf)
        accs[cf] = __builtin_amdgcn_mfma_f32_16x16x32_bf16(aq[ks], bk[cf][ks], accs[cf], 0, 0, 0);
#pragma unroll
    for (int cf = 0; cf < 4; ++cf) {
      int col = t * 64 + cf * 16 + li;
      float c0 = scomp[col], c1 = scomp[1024 + col];
      float c2 = scomp[2048 + col], c3 = scomp[3072 + col];
#pragma unroll
      for (int r = 0; r < 4; ++r) {
        float v = accs[cf][r] * 0.125f;
        float a = __expf(v - mrow[r]) * inv_l[r];
        float cc = crow[0][r] * c0 + crow[1][r] * c1 + crow[2][r] * c2 + crow[3][r] * c3;
        float tv = __expf(a * cc);
        unsigned short hv = f2b(tv);
        sum2[r] += b2f(hv);  // denominator consistent with bf16 numerator
        wbuf[(g * 4 + r) * 72 + cf * 16 + li] = hv;
      }
    }
    bf16x8 aw[2], bv[4][2];
#pragma unroll
    for (int ks = 0; ks < 2; ++ks)
      aw[ks] = *reinterpret_cast<const bf16x8*>(&wbuf[li * 72 + ks * 32 + g * 8]);
#pragma unroll
    for (int cf = 0; cf < 4; ++cf)
#pragma unroll
      for (int ks = 0; ks < 2; ++ks) {
        int d = cf * 16 + li, s = ks * 4 + g;
        bv[cf][ks] = *reinterpret_cast<const bf16x8*>(&sVT[(d * 8 + (s ^ (d & 7))) * 8]);
      }
#pragma unroll
    for (int ks = 0; ks < 2; ++ks)
#pragma unroll
      for (int cf = 0; cf < 4; ++cf)
        acco[cf] = __builtin_amdgcn_mfma_f32_16x16x32_bf16(aw[ks], bv[cf][ks], acco[cf], 0, 0, 0);
  }
#pragma unroll
  for (int r = 0; r < 4; ++r) {
#pragma unroll
    for (int o = 8; o > 0; o >>= 1) sum2[r] += __shfl_xor(sum2[r], o);
  }
#pragma unroll
  for (int cf = 0; cf < 4; ++cf)
#pragma unroll
    for (int r = 0; r < 4; ++r) {
      int qrow = qrow0 + g * 4 + r;
      yhat[((size_t)(f * NTOK + qrow)) * DIN + h * HD + cf * 16 + li] = acco[cf][r] / sum2[r];
    }
}

extern "C" void kernel_launch(void* const* d_in, const int* in_sizes, int n_in,
                              void* d_out, int out_size, void* d_ws, size_t ws_size,
                              hipStream_t stream) {
  const float* x      = (const float*)d_in[0];
  const float* compat = (const float*)d_in[1];
  const float* code   = (const float*)d_in[2];
  const float* w_c    = (const float*)d_in[3];
  const float* W_qkv  = (const float*)d_in[4];
  const float* b_qkv  = (const float*)d_in[5];
  const float* W_proj = (const float*)d_in[6];
  const float* b_proj = (const float*)d_in[7];
  const float* lnqg   = (const float*)d_in[8];
  const float* lnqb   = (const float*)d_in[9];
  const float* lnpg   = (const float*)d_in[10];
  const float* lnpb   = (const float*)d_in[11];
  float* out = (float*)d_out;

  float* cmq  = (float*)d_ws;
  float* cmp_ = cmq + NF * DIN;
  unsigned short* Wqh  = (unsigned short*)(cmp_ + NF * DIN);
  unsigned short* Wph  = Wqh + NQKV * DIN;                  // 786432
  unsigned short* qkvh = Wph + DIN * DIN;                   // 262144
  unsigned short* vTh  = qkvh + (size_t)NF * NTOK * NQKV;   // 6291456
  float* yhat = (float*)(vTh + (size_t)NF * DIN * NTOK);    // 2097152 shorts

  prep_convert<<<257, 512, 0, stream>>>(code, w_c, lnqg, lnqb, lnpg, lnpb,
                                        W_qkv, W_proj, cmq, cmp_, Wqh, Wph);
  gemm_mod<NQKV, true, true><<<dim3(12, 32), 256, 0, stream>>>(
      x, 1023, cmq, Wqh, b_qkv, qkvh, nullptr, vTh);
  attn_mfma<<<dim3(16, 32), 256, 0, stream>>>(qkvh, vTh, compat, yhat);
  gemm_mod<DIN, false, false><<<dim3(4, 32), 256, 0, stream>>>(
      yhat, 4095, cmp_, Wph, b_proj, nullptr, out, nullptr);
}

// Round 4
// 174.019 us; speedup vs baseline: 4.4048x; 1.1076x over previous
//
#include <hip/hip_runtime.h>
#include <hip/hip_bf16.h>
#include <math.h>

#define NTOK 1024
#define DIN  512
#define NF   4
#define DCOND 128
#define H    8
#define HD   64
#define NQKV 1536

typedef __attribute__((ext_vector_type(8))) short bf16x8;
typedef __attribute__((ext_vector_type(4))) float f32x4;
typedef __attribute__((ext_vector_type(4))) unsigned short us4;

__device__ __forceinline__ unsigned short f2b(float f) {
  union { float f; unsigned int u; } v; v.f = f;
  unsigned int r = v.u + 0x7fffu + ((v.u >> 16) & 1u);
  return (unsigned short)(r >> 16);
}

__device__ __forceinline__ float b2f(unsigned short h) {
  union { unsigned int u; float f; } v; v.u = ((unsigned int)h) << 16;
  return v.f;
}

__device__ __forceinline__ void gl_lds16(const void* g, void* l) {
  __builtin_amdgcn_global_load_lds(
      (const __attribute__((address_space(1))) unsigned int*)g,
      (__attribute__((address_space(3))) unsigned int*)l, 16, 0, 0);
}

// ---------------- LN of (w_c@code).T -> cmq, cmp_ (f32) ----------------
__global__ void ln_kernel(const float* __restrict__ code, const float* __restrict__ w_c,
                          const float* __restrict__ lnqg, const float* __restrict__ lnqb,
                          const float* __restrict__ lnpg, const float* __restrict__ lnpb,
                          float* __restrict__ cmq, float* __restrict__ cmp_) {
  const int i = threadIdx.x;          // 0..511
  const int w = i >> 6, lane = i & 63;
  float t[NF] = {0.f, 0.f, 0.f, 0.f};
  const float* wr = w_c + i * DCOND;
#pragma unroll 8
  for (int k = 0; k < DCOND; k += 4) {
    float4 wv = *reinterpret_cast<const float4*>(wr + k);
    float4 c0 = *reinterpret_cast<const float4*>(&code[k * 4]);
    float4 c1 = *reinterpret_cast<const float4*>(&code[(k + 1) * 4]);
    float4 c2 = *reinterpret_cast<const float4*>(&code[(k + 2) * 4]);
    float4 c3 = *reinterpret_cast<const float4*>(&code[(k + 3) * 4]);
    t[0] += wv.x * c0.x + wv.y * c1.x + wv.z * c2.x + wv.w * c3.x;
    t[1] += wv.x * c0.y + wv.y * c1.y + wv.z * c2.y + wv.w * c3.y;
    t[2] += wv.x * c0.z + wv.y * c1.z + wv.z * c2.z + wv.w * c3.z;
    t[3] += wv.x * c0.w + wv.y * c1.w + wv.z * c2.w + wv.w * c3.w;
  }
  __shared__ float redS[8], redQ[8];
#pragma unroll
  for (int f = 0; f < NF; ++f) {
    float s = t[f], q = t[f] * t[f];
#pragma unroll
    for (int o = 32; o > 0; o >>= 1) { s += __shfl_xor(s, o); q += __shfl_xor(q, o); }
    if (lane == 0) { redS[w] = s; redQ[w] = q; }
    __syncthreads();
    float S = 0.f, Q = 0.f;
#pragma unroll
    for (int j = 0; j < 8; ++j) { S += redS[j]; Q += redQ[j]; }
    float mu = S * (1.f / 512.f);
    float var = Q * (1.f / 512.f) - mu * mu;
    float rstd = rsqrtf(var + 1e-5f);
    float nv = (t[f] - mu) * rstd;
    cmq[f * DIN + i]  = nv * lnqg[i] + lnqb[i];
    cmp_[f * DIN + i] = nv * lnpg[i] + lnpb[i];
    __syncthreads();
  }
}

// ---------------- prep2: W->bf16 converts + xm = bf16(x*cmq) ----------------
// blocks [0,192): Wqh; [192,256): Wph; [256,768): xm
__global__ void prep2_kernel(const float* __restrict__ W_qkv, const float* __restrict__ W_proj,
                             const float* __restrict__ x, const float* __restrict__ cmq,
                             unsigned short* __restrict__ Wqh, unsigned short* __restrict__ Wph,
                             unsigned short* __restrict__ xm) {
  const int bid = blockIdx.x, tid = threadIdx.x;
  if (bid < 256) {
    const float* src; unsigned short* dst; int e;
    if (bid < 192) { src = W_qkv; dst = Wqh; e = bid * 4096 + tid * 16; }
    else { src = W_proj; dst = Wph; e = (bid - 192) * 4096 + tid * 16; }
#pragma unroll
    for (int j = 0; j < 4; ++j) {
      float4 a = *reinterpret_cast<const float4*>(&src[e + j * 4]);
      us4 p = { f2b(a.x), f2b(a.y), f2b(a.z), f2b(a.w) };
      *reinterpret_cast<us4*>(&dst[e + j * 4]) = p;
    }
  } else {
    int e = (bid - 256) * 4096 + tid * 16;   // [4][1024][512] flat
    int row = e >> 9, d = e & 511;
    int f = row >> 10, n = row & 1023;
    const float* xr = x + (size_t)n * DIN + d;
    const float* cr = cmq + f * DIN + d;
#pragma unroll
    for (int j = 0; j < 4; ++j) {
      float4 a = *reinterpret_cast<const float4*>(xr + j * 4);
      float4 c = *reinterpret_cast<const float4*>(cr + j * 4);
      us4 p = { f2b(a.x * c.x), f2b(a.y * c.y), f2b(a.z * c.z), f2b(a.w * c.w) };
      *reinterpret_cast<us4*>(&xm[e + j * 4]) = p;
    }
  }
}

// ---------------- bf16 GEMM: out[row,c] = Ah[row,:] @ Wh[c,:] + bias[c] ----------------
template<int NCOL, bool OUT_BF16, bool WRITE_VT>
__global__ __launch_bounds__(256, 3)
void gemm_bb(const unsigned short* __restrict__ Ah,   // [4096][512]
             const unsigned short* __restrict__ Wh,   // [NCOL][512]
             const float* __restrict__ bias,
             unsigned short* __restrict__ outH,
             float* __restrict__ outF,
             unsigned short* __restrict__ vT) {
  __shared__ __align__(16) unsigned short sA[2][4096];
  __shared__ __align__(16) unsigned short sB[2][4096];
  const int tid = threadIdx.x;
  const int lane = tid & 63, w = tid >> 6;
  const int li = lane & 15, g = lane >> 4;
  const int wr = (w >> 1) * 64, wc = (w & 1) * 64;
  const int row0 = blockIdx.y * 128, col0 = blockIdx.x * 128;
  const int f = row0 >> 10;

  f32x4 acc[4][4];
#pragma unroll
  for (int m = 0; m < 4; ++m)
#pragma unroll
    for (int n = 0; n < 4; ++n) acc[m][n] = (f32x4){0.f, 0.f, 0.f, 0.f};

  auto stage = [&](int buf, int k0) {
#pragma unroll
    for (int j = 0; j < 2; ++j) {
      int slot = w * 128 + j * 64 + lane;
      int r = slot >> 2, sp = slot & 3, s = sp ^ ((r >> 1) & 3);
      gl_lds16(Ah + (size_t)(row0 + r) * DIN + k0 + s * 8, &sA[buf][(w * 128 + j * 64) * 8]);
    }
#pragma unroll
    for (int j = 0; j < 2; ++j) {
      int slot = w * 128 + j * 64 + lane;
      int r = slot >> 2, sp = slot & 3, s = sp ^ ((r >> 1) & 3);
      gl_lds16(Wh + (size_t)(col0 + r) * DIN + k0 + s * 8, &sB[buf][(w * 128 + j * 64) * 8]);
    }
  };

  stage(0, 0);
  __syncthreads();
  for (int it = 0; it < 16; ++it) {
    int buf = it & 1;
    if (it < 15) stage(buf ^ 1, (it + 1) * 32);
    bf16x8 aF[4], bF[4];
#pragma unroll
    for (int m = 0; m < 4; ++m) {
      int ra = wr + m * 16 + li;
      aF[m] = *reinterpret_cast<const bf16x8*>(&sA[buf][(ra * 4 + (g ^ ((ra >> 1) & 3))) * 8]);
    }
#pragma unroll
    for (int n = 0; n < 4; ++n) {
      int cb = wc + n * 16 + li;
      bF[n] = *reinterpret_cast<const bf16x8*>(&sB[buf][(cb * 4 + (g ^ ((cb >> 1) & 3))) * 8]);
    }
#pragma unroll
    for (int m = 0; m < 4; ++m)
#pragma unroll
      for (int n = 0; n < 4; ++n)
        acc[m][n] = __builtin_amdgcn_mfma_f32_16x16x32_bf16(aF[m], bF[n], acc[m][n], 0, 0, 0);
    __syncthreads();
  }
  // epilogue
#pragma unroll
  for (int n = 0; n < 4; ++n) {
    int col = col0 + wc + n * 16 + li;
    float bb = bias[col];
#pragma unroll
    for (int m = 0; m < 4; ++m) {
      int rb = row0 + wr + m * 16 + g * 4;
      f32x4 v = acc[m][n];
      if constexpr (OUT_BF16) {
        if (WRITE_VT && col >= 1024) {
          int tok0 = rb & 1023;
          us4 pk;
#pragma unroll
          for (int r = 0; r < 4; ++r) pk[r] = f2b(v[r] + bb);
          *reinterpret_cast<us4*>(&vT[((size_t)(f * 512 + (col - 1024))) * NTOK + tok0]) = pk;
        } else {
#pragma unroll
          for (int r = 0; r < 4; ++r)
            outH[(size_t)(rb + r) * NCOL + col] = f2b(v[r] + bb);
        }
      } else {
#pragma unroll
        for (int r = 0; r < 4; ++r)
          outF[(size_t)(rb + r) * NCOL + col] = v[r] + bb;
      }
    }
  }
}

// ---------------- MFMA attention, double softmax, two-pass flash, pipelined ----------------
__global__ __launch_bounds__(256, 3)
void attn_mfma(const unsigned short* __restrict__ qkvh,  // [4][1024][1536] bf16 (Q,K cols)
               const unsigned short* __restrict__ vTh,   // [4][512][1024] bf16 (V^T)
               const float* __restrict__ comp,           // [4][1024]
               const float* __restrict__ cmp_,           // [4][512] f32
               unsigned short* __restrict__ ym) {        // [4][1024][512] bf16 (scaled by cmp_)
  __shared__ __align__(16) unsigned short sK[2][4096];
  __shared__ __align__(16) unsigned short sVT[2][4096];
  __shared__ __align__(16) unsigned short sW[4][16 * 72];
  __shared__ __align__(16) unsigned short scompH[4096];
  const int tid = threadIdx.x, lane = tid & 63, w = tid >> 6;
  const int li = lane & 15, g = lane >> 4;
  const int hf = blockIdx.x;            // 0..31 (same-hf blocks share XCD)
  const int qt = blockIdx.y;            // 0..15
  const int h = hf >> 2, f = hf & 3;

  {
    int e = tid * 16;
#pragma unroll
    for (int j = 0; j < 4; ++j) {
      float4 a = *reinterpret_cast<const float4*>(&comp[e + j * 4]);
      us4 p = { f2b(a.x), f2b(a.y), f2b(a.z), f2b(a.w) };
      *reinterpret_cast<us4*>(&scompH[e + j * 4]) = p;
    }
  }

  const int qrow0 = qt * 64 + w * 16;
  const unsigned short* qbase = qkvh + ((size_t)(f * NTOK + qrow0 + li)) * NQKV + h * HD;
  bf16x8 aq[2];
  aq[0] = *reinterpret_cast<const bf16x8*>(qbase + g * 8);
  aq[1] = *reinterpret_cast<const bf16x8*>(qbase + 32 + g * 8);

  float crow[4][4];
#pragma unroll
  for (int ff = 0; ff < 4; ++ff)
#pragma unroll
    for (int r = 0; r < 4; ++r)
      crow[ff][r] = comp[ff * NTOK + qrow0 + g * 4 + r];

  const unsigned short* kb = qkvh + ((size_t)(f * NTOK)) * NQKV + DIN + h * HD;
  const unsigned short* vb = vTh + ((size_t)(f * DIN + h * HD)) * NTOK;

  auto stage_k = [&](int buf, int t) {
#pragma unroll
    for (int j = 0; j < 2; ++j) {
      int slot = w * 128 + j * 64 + lane;
      int tok = slot >> 3, sp = slot & 7, s = sp ^ (tok & 7);
      gl_lds16(kb + (size_t)(t * 64 + tok) * NQKV + s * 8, &sK[buf][(w * 128 + j * 64) * 8]);
    }
  };
  auto stage_v = [&](int buf, int t) {
#pragma unroll
    for (int j = 0; j < 2; ++j) {
      int slot = w * 128 + j * 64 + lane;
      int d = slot >> 3, sp = slot & 7, s = sp ^ (d & 7);
      gl_lds16(vb + (size_t)d * NTOK + t * 64 + s * 8, &sVT[buf][(w * 128 + j * 64) * 8]);
    }
  };

  float mrow[4], lrow[4];
#pragma unroll
  for (int r = 0; r < 4; ++r) { mrow[r] = -1e30f; lrow[r] = 0.f; }

  // ---- pass A: softmax-1 stats (pipelined) ----
  stage_k(0, 0);
  __syncthreads();
  for (int t = 0; t < 16; ++t) {
    int buf = t & 1;
    if (t < 15) stage_k(buf ^ 1, t + 1);
    bf16x8 bk[4][2];
#pragma unroll
    for (int cf = 0; cf < 4; ++cf)
#pragma unroll
      for (int ks = 0; ks < 2; ++ks) {
        int tok = cf * 16 + li, s = ks * 4 + g;
        bk[cf][ks] = *reinterpret_cast<const bf16x8*>(&sK[buf][(tok * 8 + (s ^ (tok & 7))) * 8]);
      }
    f32x4 accs[4];
#pragma unroll
    for (int cf = 0; cf < 4; ++cf) accs[cf] = (f32x4){0.f, 0.f, 0.f, 0.f};
#pragma unroll
    for (int ks = 0; ks < 2; ++ks)
#pragma unroll
      for (int cf = 0; cf < 4; ++cf)
        accs[cf] = __builtin_amdgcn_mfma_f32_16x16x32_bf16(aq[ks], bk[cf][ks], accs[cf], 0, 0, 0);
#pragma unroll
    for (int r = 0; r < 4; ++r) {
      float v0 = accs[0][r] * 0.125f, v1 = accs[1][r] * 0.125f;
      float v2 = accs[2][r] * 0.125f, v3 = accs[3][r] * 0.125f;
      float tm = fmaxf(fmaxf(v0, v1), fmaxf(v2, v3));
#pragma unroll
      for (int o = 8; o > 0; o >>= 1) tm = fmaxf(tm, __shfl_xor(tm, o));
      float nm = fmaxf(mrow[r], tm);
      float ssum = __expf(v0 - nm) + __expf(v1 - nm) + __expf(v2 - nm) + __expf(v3 - nm);
#pragma unroll
      for (int o = 8; o > 0; o >>= 1) ssum += __shfl_xor(ssum, o);
      lrow[r] = lrow[r] * __expf(mrow[r] - nm) + ssum;
      mrow[r] = nm;
    }
    __syncthreads();
  }
  float inv_l[4];
#pragma unroll
  for (int r = 0; r < 4; ++r) inv_l[r] = 1.f / lrow[r];

  // ---- pass B: recompute S, t=exp(attn*cc), PV + sum2 (pipelined) ----
  f32x4 acco[4];
  float sum2[4] = {0.f, 0.f, 0.f, 0.f};
#pragma unroll
  for (int cf = 0; cf < 4; ++cf) acco[cf] = (f32x4){0.f, 0.f, 0.f, 0.f};
  unsigned short* wbuf = &sW[w][0];

  stage_k(0, 0);
  stage_v(0, 0);
  __syncthreads();
  for (int t = 0; t < 16; ++t) {
    int buf = t & 1;
    if (t < 15) { stage_k(buf ^ 1, t + 1); stage_v(buf ^ 1, t + 1); }
    bf16x8 bk[4][2];
#pragma unroll
    for (int cf = 0; cf < 4; ++cf)
#pragma unroll
      for (int ks = 0; ks < 2; ++ks) {
        int tok = cf * 16 + li, s = ks * 4 + g;
        bk[cf][ks] = *reinterpret_cast<const bf16x8*>(&sK[buf][(tok * 8 + (s ^ (tok & 7))) * 8]);
      }
    f32x4 accs[4];
#pragma unroll
    for (int cf = 0; cf < 4; ++cf) accs[cf] = (f32x4){0.f, 0.f, 0.f, 0.f};
#pragma unroll
    for (int ks = 0; ks < 2; ++ks)
#pragma unroll
      for (int cf = 0; cf < 4; ++cf)
        accs[cf] = __builtin_amdgcn_mfma_f32_16x16x32_bf16(aq[ks], bk[cf][ks], accs[cf], 0, 0, 0);
#pragma unroll
    for (int cf = 0; cf < 4; ++cf) {
      int col = t * 64 + cf * 16 + li;
      float c0 = b2f(scompH[col]), c1 = b2f(scompH[1024 + col]);
      float c2 = b2f(scompH[2048 + col]), c3 = b2f(scompH[3072 + col]);
#pragma unroll
      for (int r = 0; r < 4; ++r) {
        float v = accs[cf][r] * 0.125f;
        float a = __expf(v - mrow[r]) * inv_l[r];
        float cc = crow[0][r] * c0 + crow[1][r] * c1 + crow[2][r] * c2 + crow[3][r] * c3;
        float tv = __expf(a * cc);
        unsigned short hv = f2b(tv);
        sum2[r] += b2f(hv);
        wbuf[(g * 4 + r) * 72 + cf * 16 + li] = hv;
      }
    }
    bf16x8 aw[2], bv[4][2];
#pragma unroll
    for (int ks = 0; ks < 2; ++ks)
      aw[ks] = *reinterpret_cast<const bf16x8*>(&wbuf[li * 72 + ks * 32 + g * 8]);
#pragma unroll
    for (int cf = 0; cf < 4; ++cf)
#pragma unroll
      for (int ks = 0; ks < 2; ++ks) {
        int d = cf * 16 + li, s = ks * 4 + g;
        bv[cf][ks] = *reinterpret_cast<const bf16x8*>(&sVT[buf][(d * 8 + (s ^ (d & 7))) * 8]);
      }
#pragma unroll
    for (int ks = 0; ks < 2; ++ks)
#pragma unroll
      for (int cf = 0; cf < 4; ++cf)
        acco[cf] = __builtin_amdgcn_mfma_f32_16x16x32_bf16(aw[ks], bv[cf][ks], acco[cf], 0, 0, 0);
    __syncthreads();
  }
#pragma unroll
  for (int r = 0; r < 4; ++r) {
#pragma unroll
    for (int o = 8; o > 0; o >>= 1) sum2[r] += __shfl_xor(sum2[r], o);
  }
  float cscale[4];
#pragma unroll
  for (int cf = 0; cf < 4; ++cf) cscale[cf] = cmp_[f * DIN + h * HD + cf * 16 + li];
#pragma unroll
  for (int cf = 0; cf < 4; ++cf)
#pragma unroll
    for (int r = 0; r < 4; ++r) {
      int qrow = qrow0 + g * 4 + r;
      ym[((size_t)(f * NTOK + qrow)) * DIN + h * HD + cf * 16 + li] =
          f2b(acco[cf][r] / sum2[r] * cscale[cf]);
    }
}

extern "C" void kernel_launch(void* const* d_in, const int* in_sizes, int n_in,
                              void* d_out, int out_size, void* d_ws, size_t ws_size,
                              hipStream_t stream) {
  const float* x      = (const float*)d_in[0];
  const float* compat = (const float*)d_in[1];
  const float* code   = (const float*)d_in[2];
  const float* w_c    = (const float*)d_in[3];
  const float* W_qkv  = (const float*)d_in[4];
  const float* b_qkv  = (const float*)d_in[5];
  const float* W_proj = (const float*)d_in[6];
  const float* b_proj = (const float*)d_in[7];
  const float* lnqg   = (const float*)d_in[8];
  const float* lnqb   = (const float*)d_in[9];
  const float* lnpg   = (const float*)d_in[10];
  const float* lnpb   = (const float*)d_in[11];
  float* out = (float*)d_out;

  float* cmq  = (float*)d_ws;
  float* cmp_ = cmq + NF * DIN;
  unsigned short* Wqh  = (unsigned short*)(cmp_ + NF * DIN);
  unsigned short* Wph  = Wqh + (size_t)NQKV * DIN;          // 786432
  unsigned short* xm   = Wph + (size_t)DIN * DIN;           // 262144
  unsigned short* qkvh = xm + (size_t)NF * NTOK * DIN;      // 2097152
  unsigned short* vTh  = qkvh + (size_t)NF * NTOK * NQKV;   // 6291456
  unsigned short* ym   = vTh + (size_t)NF * DIN * NTOK;     // 2097152

  ln_kernel<<<1, 512, 0, stream>>>(code, w_c, lnqg, lnqb, lnpg, lnpb, cmq, cmp_);
  prep2_kernel<<<768, 256, 0, stream>>>(W_qkv, W_proj, x, cmq, Wqh, Wph, xm);
  gemm_bb<NQKV, true, true><<<dim3(12, 32), 256, 0, stream>>>(
      xm, Wqh, b_qkv, qkvh, nullptr, vTh);
  attn_mfma<<<dim3(32, 16), 256, 0, stream>>>(qkvh, vTh, compat, cmp_, ym);
  gemm_bb<DIN, false, false><<<dim3(4, 32), 256, 0, stream>>>(
      ym, Wph, b_proj, nullptr, out, nullptr);
}

// Round 5
// 173.691 us; speedup vs baseline: 4.4131x; 1.0019x over previous
//
#include <hip/hip_runtime.h>
#include <hip/hip_bf16.h>
#include <math.h>

#define NTOK 1024
#define DIN  512
#define NF   4
#define DCOND 128
#define H    8
#define HD   64
#define NQKV 1536

typedef __attribute__((ext_vector_type(8))) short bf16x8;
typedef __attribute__((ext_vector_type(4))) float f32x4;
typedef __attribute__((ext_vector_type(4))) unsigned short us4;

__device__ __forceinline__ unsigned short f2b(float f) {
  union { float f; unsigned int u; } v; v.f = f;
  unsigned int r = v.u + 0x7fffu + ((v.u >> 16) & 1u);
  return (unsigned short)(r >> 16);
}

__device__ __forceinline__ float b2f(unsigned short h) {
  union { unsigned int u; float f; } v; v.u = ((unsigned int)h) << 16;
  return v.f;
}

__device__ __forceinline__ float asf(unsigned int u) {
  union { unsigned int u; float f; } v; v.u = u;
  return v.f;
}

__device__ __forceinline__ void gl_lds16(const void* g, void* l) {
  __builtin_amdgcn_global_load_lds(
      (const __attribute__((address_space(1))) unsigned int*)g,
      (__attribute__((address_space(3))) unsigned int*)l, 16, 0, 0);
}

// ---------------- LN of (w_c@code).T -> cmq, cmp_ (f32) ----------------
__global__ void ln_kernel(const float* __restrict__ code, const float* __restrict__ w_c,
                          const float* __restrict__ lnqg, const float* __restrict__ lnqb,
                          const float* __restrict__ lnpg, const float* __restrict__ lnpb,
                          float* __restrict__ cmq, float* __restrict__ cmp_) {
  const int i = threadIdx.x;          // 0..511
  const int w = i >> 6, lane = i & 63;
  float t[NF] = {0.f, 0.f, 0.f, 0.f};
  const float* wr = w_c + i * DCOND;
#pragma unroll 8
  for (int k = 0; k < DCOND; k += 4) {
    float4 wv = *reinterpret_cast<const float4*>(wr + k);
    float4 c0 = *reinterpret_cast<const float4*>(&code[k * 4]);
    float4 c1 = *reinterpret_cast<const float4*>(&code[(k + 1) * 4]);
    float4 c2 = *reinterpret_cast<const float4*>(&code[(k + 2) * 4]);
    float4 c3 = *reinterpret_cast<const float4*>(&code[(k + 3) * 4]);
    t[0] += wv.x * c0.x + wv.y * c1.x + wv.z * c2.x + wv.w * c3.x;
    t[1] += wv.x * c0.y + wv.y * c1.y + wv.z * c2.y + wv.w * c3.y;
    t[2] += wv.x * c0.z + wv.y * c1.z + wv.z * c2.z + wv.w * c3.z;
    t[3] += wv.x * c0.w + wv.y * c1.w + wv.z * c2.w + wv.w * c3.w;
  }
  __shared__ float redS[8], redQ[8];
#pragma unroll
  for (int f = 0; f < NF; ++f) {
    float s = t[f], q = t[f] * t[f];
#pragma unroll
    for (int o = 32; o > 0; o >>= 1) { s += __shfl_xor(s, o); q += __shfl_xor(q, o); }
    if (lane == 0) { redS[w] = s; redQ[w] = q; }
    __syncthreads();
    float S = 0.f, Q = 0.f;
#pragma unroll
    for (int j = 0; j < 8; ++j) { S += redS[j]; Q += redQ[j]; }
    float mu = S * (1.f / 512.f);
    float var = Q * (1.f / 512.f) - mu * mu;
    float rstd = rsqrtf(var + 1e-5f);
    float nv = (t[f] - mu) * rstd;
    cmq[f * DIN + i]  = nv * lnqg[i] + lnqb[i];
    cmp_[f * DIN + i] = nv * lnpg[i] + lnpb[i];
    __syncthreads();
  }
}

// ---------------- prep2: W->bf16 converts + xm = bf16(x*cmq) ----------------
__global__ void prep2_kernel(const float* __restrict__ W_qkv, const float* __restrict__ W_proj,
                             const float* __restrict__ x, const float* __restrict__ cmq,
                             unsigned short* __restrict__ Wqh, unsigned short* __restrict__ Wph,
                             unsigned short* __restrict__ xm) {
  const int bid = blockIdx.x, tid = threadIdx.x;
  if (bid < 256) {
    const float* src; unsigned short* dst; int e;
    if (bid < 192) { src = W_qkv; dst = Wqh; e = bid * 4096 + tid * 16; }
    else { src = W_proj; dst = Wph; e = (bid - 192) * 4096 + tid * 16; }
#pragma unroll
    for (int j = 0; j < 4; ++j) {
      float4 a = *reinterpret_cast<const float4*>(&src[e + j * 4]);
      us4 p = { f2b(a.x), f2b(a.y), f2b(a.z), f2b(a.w) };
      *reinterpret_cast<us4*>(&dst[e + j * 4]) = p;
    }
  } else {
    int e = (bid - 256) * 4096 + tid * 16;   // [4][1024][512] flat
    int row = e >> 9, d = e & 511;
    int f = row >> 10, n = row & 1023;
    const float* xr = x + (size_t)n * DIN + d;
    const float* cr = cmq + f * DIN + d;
#pragma unroll
    for (int j = 0; j < 4; ++j) {
      float4 a = *reinterpret_cast<const float4*>(xr + j * 4);
      float4 c = *reinterpret_cast<const float4*>(cr + j * 4);
      us4 p = { f2b(a.x * c.x), f2b(a.y * c.y), f2b(a.z * c.z), f2b(a.w * c.w) };
      *reinterpret_cast<us4*>(&xm[e + j * 4]) = p;
    }
  }
}

// ---------------- bf16 GEMM, 64x64 tile: out[row,c] = Ah[row,:] @ Wh[c,:] + bias[c] ----------------
template<int NCOL, bool OUT_BF16, bool WRITE_VT, bool SCALE_Q>
__global__ __launch_bounds__(256, 6)
void gemm64(const unsigned short* __restrict__ Ah,   // [4096][512]
            const unsigned short* __restrict__ Wh,   // [NCOL][512]
            const float* __restrict__ bias,
            unsigned short* __restrict__ outH,
            float* __restrict__ outF,
            unsigned short* __restrict__ vT) {
  __shared__ __align__(16) unsigned short sA[2][2048];
  __shared__ __align__(16) unsigned short sB[2][2048];
  const int tid = threadIdx.x;
  const int lane = tid & 63, w = tid >> 6;
  const int li = lane & 15, g = lane >> 4;
  const int wr = (w >> 1) * 32, wc = (w & 1) * 32;
  const int row0 = blockIdx.y * 64, col0 = blockIdx.x * 64;
  const int f = row0 >> 10;
  const int sr = tid >> 2, sp = tid & 3;
  const int ss = sp ^ ((sr >> 1) & 3);

  f32x4 acc[2][2];
#pragma unroll
  for (int m = 0; m < 2; ++m)
#pragma unroll
    for (int n = 0; n < 2; ++n) acc[m][n] = (f32x4){0.f, 0.f, 0.f, 0.f};

  const unsigned short* aSrc = Ah + (size_t)(row0 + sr) * DIN + ss * 8;
  const unsigned short* bSrc = Wh + (size_t)(col0 + sr) * DIN + ss * 8;

  // prologue stage
  gl_lds16(aSrc, &sA[0][w * 512]);
  gl_lds16(bSrc, &sB[0][w * 512]);
  __syncthreads();
  for (int it = 0; it < 16; ++it) {
    int buf = it & 1;
    if (it < 15) {
      gl_lds16(aSrc + (it + 1) * 32, &sA[buf ^ 1][w * 512]);
      gl_lds16(bSrc + (it + 1) * 32, &sB[buf ^ 1][w * 512]);
    }
    bf16x8 aF[2], bF[2];
#pragma unroll
    for (int m = 0; m < 2; ++m) {
      int ra = wr + m * 16 + li;
      aF[m] = *reinterpret_cast<const bf16x8*>(&sA[buf][(ra * 4 + (g ^ ((ra >> 1) & 3))) * 8]);
    }
#pragma unroll
    for (int n = 0; n < 2; ++n) {
      int cb = wc + n * 16 + li;
      bF[n] = *reinterpret_cast<const bf16x8*>(&sB[buf][(cb * 4 + (g ^ ((cb >> 1) & 3))) * 8]);
    }
#pragma unroll
    for (int m = 0; m < 2; ++m)
#pragma unroll
      for (int n = 0; n < 2; ++n)
        acc[m][n] = __builtin_amdgcn_mfma_f32_16x16x32_bf16(aF[m], bF[n], acc[m][n], 0, 0, 0);
    __syncthreads();
  }
  // epilogue
#pragma unroll
  for (int n = 0; n < 2; ++n) {
    int col = col0 + wc + n * 16 + li;
    float bb = bias[col];
    float sc = (SCALE_Q && col < DIN) ? 0.125f : 1.0f;
#pragma unroll
    for (int m = 0; m < 2; ++m) {
      int rb = row0 + wr + m * 16 + g * 4;
      f32x4 v = acc[m][n];
      if constexpr (OUT_BF16) {
        if (WRITE_VT && col >= 1024) {
          int tok0 = rb & 1023;
          us4 pk;
#pragma unroll
          for (int r = 0; r < 4; ++r) pk[r] = f2b(v[r] + bb);
          *reinterpret_cast<us4*>(&vT[((size_t)(f * 512 + (col - 1024))) * NTOK + tok0]) = pk;
        } else {
#pragma unroll
          for (int r = 0; r < 4; ++r)
            outH[(size_t)(rb + r) * NCOL + col] = f2b((v[r] + bb) * sc);
        }
      } else {
#pragma unroll
        for (int r = 0; r < 4; ++r)
          outF[(size_t)(rb + r) * NCOL + col] = v[r] + bb;
      }
    }
  }
}

// ---------------- MFMA attention v2: 32 q-rows/block, waves = (rt, ch) ----------------
__global__ __launch_bounds__(256, 3)
void attn_mfma2(const unsigned short* __restrict__ qkvh,  // [4][1024][1536] (Q pre-scaled 1/8)
                const unsigned short* __restrict__ vTh,   // [4][512][1024] V^T
                const float* __restrict__ comp,           // [4][1024]
                const float* __restrict__ cmp_,           // [4][512]
                unsigned short* __restrict__ ym) {        // [4][1024][512] bf16*cmp_
  __shared__ __align__(16) unsigned short sK[2][4096];
  __shared__ __align__(16) unsigned short sV[2][4096];
  __shared__ __align__(16) unsigned short sW[4][16 * 72];
  __shared__ unsigned int sc01[1024], sc23[1024];
  __shared__ float lred[2][2][16];
  __shared__ float s2red[2][16];
  const int tid = threadIdx.x, lane = tid & 63, w = tid >> 6;
  const int li = lane & 15, g = lane >> 4;
  const int rt = w & 1, ch = w >> 1;
  const int hf = blockIdx.x, qt = blockIdx.y;
  const int h = hf >> 2, f = hf & 3;

  // pack comp rows into bf16 pairs
  {
    int c = tid * 4;
    float4 a0 = *reinterpret_cast<const float4*>(&comp[c]);
    float4 a1 = *reinterpret_cast<const float4*>(&comp[1024 + c]);
    float4 a2 = *reinterpret_cast<const float4*>(&comp[2048 + c]);
    float4 a3 = *reinterpret_cast<const float4*>(&comp[3072 + c]);
    sc01[c + 0] = f2b(a0.x) | ((unsigned int)f2b(a1.x) << 16);
    sc01[c + 1] = f2b(a0.y) | ((unsigned int)f2b(a1.y) << 16);
    sc01[c + 2] = f2b(a0.z) | ((unsigned int)f2b(a1.z) << 16);
    sc01[c + 3] = f2b(a0.w) | ((unsigned int)f2b(a1.w) << 16);
    sc23[c + 0] = f2b(a2.x) | ((unsigned int)f2b(a3.x) << 16);
    sc23[c + 1] = f2b(a2.y) | ((unsigned int)f2b(a3.y) << 16);
    sc23[c + 2] = f2b(a2.z) | ((unsigned int)f2b(a3.z) << 16);
    sc23[c + 3] = f2b(a2.w) | ((unsigned int)f2b(a3.w) << 16);
  }

  const int qrow0 = qt * 32 + rt * 16;
  const unsigned short* qbase = qkvh + ((size_t)(f * NTOK + qrow0 + li)) * NQKV + h * HD;
  bf16x8 aq[2];
  aq[0] = *reinterpret_cast<const bf16x8*>(qbase + g * 8);
  aq[1] = *reinterpret_cast<const bf16x8*>(qbase + 32 + g * 8);

  float crow[4][4];
#pragma unroll
  for (int ff = 0; ff < 4; ++ff)
#pragma unroll
    for (int r = 0; r < 4; ++r)
      crow[ff][r] = comp[ff * NTOK + qrow0 + g * 4 + r];

  const unsigned short* kb = qkvh + ((size_t)(f * NTOK)) * NQKV + DIN + h * HD;
  const unsigned short* vb = vTh + ((size_t)(f * DIN + h * HD)) * NTOK;

  auto stageK = [&](unsigned short* dst, int t) {
#pragma unroll
    for (int j = 0; j < 8; ++j) {
      int slot = j * 64 + lane;
      int tok = slot >> 3, sp = slot & 7, s = sp ^ (tok & 7);
      gl_lds16(kb + (size_t)(t * 64 + tok) * NQKV + s * 8, dst + j * 512);
    }
  };
  auto stageV = [&](unsigned short* dst, int t) {
#pragma unroll
    for (int j = 0; j < 8; ++j) {
      int slot = j * 64 + lane;
      int d = slot >> 3, sp = slot & 7, s = sp ^ (d & 7);
      gl_lds16(vb + (size_t)d * NTOK + t * 64 + s * 8, dst + j * 512);
    }
  };

  // ---- pass A: l = sum(exp(S)) over this wave's col half ----
  float lsum[4] = {0.f, 0.f, 0.f, 0.f};
  stageK(sK[ch], ch * 8);
  __syncthreads();
  for (int tt = 0; tt < 8; ++tt) {
    unsigned short* cur = (tt & 1) ? sV[ch] : sK[ch];
    if (tt < 7) {
      unsigned short* nxt = (tt & 1) ? sK[ch] : sV[ch];
      stageK(nxt, ch * 8 + tt + 1);
    }
    bf16x8 bk[4][2];
#pragma unroll
    for (int cf = 0; cf < 4; ++cf)
#pragma unroll
      for (int ks = 0; ks < 2; ++ks) {
        int tok = cf * 16 + li, s = ks * 4 + g;
        bk[cf][ks] = *reinterpret_cast<const bf16x8*>(&cur[(tok * 8 + (s ^ (tok & 7))) * 8]);
      }
    f32x4 accs[4];
#pragma unroll
    for (int cf = 0; cf < 4; ++cf) accs[cf] = (f32x4){0.f, 0.f, 0.f, 0.f};
#pragma unroll
    for (int ks = 0; ks < 2; ++ks)
#pragma unroll
      for (int cf = 0; cf < 4; ++cf)
        accs[cf] = __builtin_amdgcn_mfma_f32_16x16x32_bf16(aq[ks], bk[cf][ks], accs[cf], 0, 0, 0);
#pragma unroll
    for (int cf = 0; cf < 4; ++cf)
#pragma unroll
      for (int r = 0; r < 4; ++r) lsum[r] += __expf(accs[cf][r]);
    __syncthreads();
  }
#pragma unroll
  for (int r = 0; r < 4; ++r) {
    lsum[r] += __shfl_xor(lsum[r], 1);
    lsum[r] += __shfl_xor(lsum[r], 2);
    lsum[r] += __shfl_xor(lsum[r], 4);
    lsum[r] += __shfl_xor(lsum[r], 8);
  }
  if (li == 0) {
#pragma unroll
    for (int r = 0; r < 4; ++r) lred[ch][rt][g * 4 + r] = lsum[r];
  }
  __syncthreads();
  float invl[4];
#pragma unroll
  for (int r = 0; r < 4; ++r)
    invl[r] = 1.f / (lred[0][rt][g * 4 + r] + lred[1][rt][g * 4 + r]);

  // ---- pass B: t = exp(a*cc), PV + sum2, over this wave's col half ----
  f32x4 acco[4];
  float sum2[4] = {0.f, 0.f, 0.f, 0.f};
#pragma unroll
  for (int cf = 0; cf < 4; ++cf) acco[cf] = (f32x4){0.f, 0.f, 0.f, 0.f};
  unsigned short* wbuf = &sW[w][0];

  for (int tt = 0; tt < 8; ++tt) {
    int t = ch * 8 + tt;
    stageK(sK[ch], t);
    stageV(sV[ch], t);
    __syncthreads();
    bf16x8 bk[4][2];
#pragma unroll
    for (int cf = 0; cf < 4; ++cf)
#pragma unroll
      for (int ks = 0; ks < 2; ++ks) {
        int tok = cf * 16 + li, s = ks * 4 + g;
        bk[cf][ks] = *reinterpret_cast<const bf16x8*>(&sK[ch][(tok * 8 + (s ^ (tok & 7))) * 8]);
      }
    f32x4 accs[4];
#pragma unroll
    for (int cf = 0; cf < 4; ++cf) accs[cf] = (f32x4){0.f, 0.f, 0.f, 0.f};
#pragma unroll
    for (int ks = 0; ks < 2; ++ks)
#pragma unroll
      for (int cf = 0; cf < 4; ++cf)
        accs[cf] = __builtin_amdgcn_mfma_f32_16x16x32_bf16(aq[ks], bk[cf][ks], accs[cf], 0, 0, 0);
#pragma unroll
    for (int cf = 0; cf < 4; ++cf) {
      int colg = t * 64 + cf * 16 + li;
      unsigned int u01 = sc01[colg], u23 = sc23[colg];
      float c0 = asf(u01 << 16), c1 = asf(u01 & 0xffff0000u);
      float c2 = asf(u23 << 16), c3 = asf(u23 & 0xffff0000u);
#pragma unroll
      for (int r = 0; r < 4; ++r) {
        float a = __expf(accs[cf][r]) * invl[r];
        float cc = crow[0][r] * c0 + crow[1][r] * c1 + crow[2][r] * c2 + crow[3][r] * c3;
        float tv = __expf(a * cc);
        unsigned short hv = f2b(tv);
        sum2[r] += b2f(hv);
        wbuf[(g * 4 + r) * 72 + cf * 16 + li] = hv;
      }
    }
    bf16x8 aw[2], bv2[4][2];
#pragma unroll
    for (int ks = 0; ks < 2; ++ks)
      aw[ks] = *reinterpret_cast<const bf16x8*>(&wbuf[li * 72 + ks * 32 + g * 8]);
#pragma unroll
    for (int cf = 0; cf < 4; ++cf)
#pragma unroll
      for (int ks = 0; ks < 2; ++ks) {
        int d = cf * 16 + li, s = ks * 4 + g;
        bv2[cf][ks] = *reinterpret_cast<const bf16x8*>(&sV[ch][(d * 8 + (s ^ (d & 7))) * 8]);
      }
#pragma unroll
    for (int ks = 0; ks < 2; ++ks)
#pragma unroll
      for (int cf = 0; cf < 4; ++cf)
        acco[cf] = __builtin_amdgcn_mfma_f32_16x16x32_bf16(aw[ks], bv2[cf][ks], acco[cf], 0, 0, 0);
    __syncthreads();
  }

  // ---- combine across ch, write ym ----
#pragma unroll
  for (int r = 0; r < 4; ++r) {
    sum2[r] += __shfl_xor(sum2[r], 1);
    sum2[r] += __shfl_xor(sum2[r], 2);
    sum2[r] += __shfl_xor(sum2[r], 4);
    sum2[r] += __shfl_xor(sum2[r], 8);
  }
  float* fred = (float*)sK;  // 16 KB reuse
  if (ch == 1) {
    if (li == 0) {
#pragma unroll
      for (int r = 0; r < 4; ++r) s2red[rt][g * 4 + r] = sum2[r];
    }
#pragma unroll
    for (int cf = 0; cf < 4; ++cf)
#pragma unroll
      for (int r = 0; r < 4; ++r)
        fred[rt * 1024 + (g * 4 + r) * 64 + cf * 16 + li] = acco[cf][r];
  }
  __syncthreads();
  if (ch == 0) {
    float invs[4];
#pragma unroll
    for (int r = 0; r < 4; ++r) invs[r] = 1.f / (sum2[r] + s2red[rt][g * 4 + r]);
    float cscale[4];
#pragma unroll
    for (int cf = 0; cf < 4; ++cf) cscale[cf] = cmp_[f * DIN + h * HD + cf * 16 + li];
#pragma unroll
    for (int cf = 0; cf < 4; ++cf)
#pragma unroll
      for (int r = 0; r < 4; ++r) {
        float v = (acco[cf][r] + fred[rt * 1024 + (g * 4 + r) * 64 + cf * 16 + li]) * invs[r];
        int qrow = qrow0 + g * 4 + r;
        ym[((size_t)(f * NTOK + qrow)) * DIN + h * HD + cf * 16 + li] = f2b(v * cscale[cf]);
      }
  }
}

extern "C" void kernel_launch(void* const* d_in, const int* in_sizes, int n_in,
                              void* d_out, int out_size, void* d_ws, size_t ws_size,
                              hipStream_t stream) {
  const float* x      = (const float*)d_in[0];
  const float* compat = (const float*)d_in[1];
  const float* code   = (const float*)d_in[2];
  const float* w_c    = (const float*)d_in[3];
  const float* W_qkv  = (const float*)d_in[4];
  const float* b_qkv  = (const float*)d_in[5];
  const float* W_proj = (const float*)d_in[6];
  const float* b_proj = (const float*)d_in[7];
  const float* lnqg   = (const float*)d_in[8];
  const float* lnqb   = (const float*)d_in[9];
  const float* lnpg   = (const float*)d_in[10];
  const float* lnpb   = (const float*)d_in[11];
  float* out = (float*)d_out;

  float* cmq  = (float*)d_ws;
  float* cmp_ = cmq + NF * DIN;
  unsigned short* Wqh  = (unsigned short*)(cmp_ + NF * DIN);
  unsigned short* Wph  = Wqh + (size_t)NQKV * DIN;
  unsigned short* xm   = Wph + (size_t)DIN * DIN;
  unsigned short* qkvh = xm + (size_t)NF * NTOK * DIN;
  unsigned short* vTh  = qkvh + (size_t)NF * NTOK * NQKV;
  unsigned short* ym   = vTh + (size_t)NF * DIN * NTOK;

  ln_kernel<<<1, 512, 0, stream>>>(code, w_c, lnqg, lnqb, lnpg, lnpb, cmq, cmp_);
  prep2_kernel<<<768, 256, 0, stream>>>(W_qkv, W_proj, x, cmq, Wqh, Wph, xm);
  gemm64<NQKV, true, true, true><<<dim3(24, 64), 256, 0, stream>>>(
      xm, Wqh, b_qkv, qkvh, nullptr, vTh);
  attn_mfma2<<<dim3(32, 32), 256, 0, stream>>>(qkvh, vTh, compat, cmp_, ym);
  gemm64<DIN, false, false, false><<<dim3(8, 64), 256, 0, stream>>>(
      ym, Wph, b_proj, nullptr, out, nullptr);
}

// Round 7
// 163.439 us; speedup vs baseline: 4.6899x; 1.0627x over previous
//
#include <hip/hip_runtime.h>
#include <hip/hip_bf16.h>
#include <math.h>

#define NTOK 1024
#define DIN  512
#define NF   4
#define DCOND 128
#define H    8
#define HD   64
#define NQKV 1536
#define LOG2E 1.4426950408889634f

typedef __attribute__((ext_vector_type(8))) short bf16x8;
typedef __attribute__((ext_vector_type(4))) float f32x4;
typedef __attribute__((ext_vector_type(4))) unsigned short us4;

__device__ __forceinline__ unsigned short f2b(float f) {
  union { float f; unsigned int u; } v; v.f = f;
  unsigned int r = v.u + 0x7fffu + ((v.u >> 16) & 1u);
  return (unsigned short)(r >> 16);
}

__device__ __forceinline__ float b2f(unsigned short h) {
  union { unsigned int u; float f; } v; v.u = ((unsigned int)h) << 16;
  return v.f;
}

__device__ __forceinline__ float asf(unsigned int u) {
  union { unsigned int u; float f; } v; v.u = u;
  return v.f;
}

__device__ __forceinline__ void gl_lds16(const void* g, void* l) {
  __builtin_amdgcn_global_load_lds(
      (const __attribute__((address_space(1))) unsigned int*)g,
      (__attribute__((address_space(3))) unsigned int*)l, 16, 0, 0);
}

// ---------------- LN of (w_c@code).T -> cmq, cmp_ (f32) ----------------
__global__ void ln_kernel(const float* __restrict__ code, const float* __restrict__ w_c,
                          const float* __restrict__ lnqg, const float* __restrict__ lnqb,
                          const float* __restrict__ lnpg, const float* __restrict__ lnpb,
                          float* __restrict__ cmq, float* __restrict__ cmp_) {
  const int i = threadIdx.x;          // 0..511
  const int w = i >> 6, lane = i & 63;
  float t[NF] = {0.f, 0.f, 0.f, 0.f};
  const float* wr = w_c + i * DCOND;
#pragma unroll 8
  for (int k = 0; k < DCOND; k += 4) {
    float4 wv = *reinterpret_cast<const float4*>(wr + k);
    float4 c0 = *reinterpret_cast<const float4*>(&code[k * 4]);
    float4 c1 = *reinterpret_cast<const float4*>(&code[(k + 1) * 4]);
    float4 c2 = *reinterpret_cast<const float4*>(&code[(k + 2) * 4]);
    float4 c3 = *reinterpret_cast<const float4*>(&code[(k + 3) * 4]);
    t[0] += wv.x * c0.x + wv.y * c1.x + wv.z * c2.x + wv.w * c3.x;
    t[1] += wv.x * c0.y + wv.y * c1.y + wv.z * c2.y + wv.w * c3.y;
    t[2] += wv.x * c0.z + wv.y * c1.z + wv.z * c2.z + wv.w * c3.z;
    t[3] += wv.x * c0.w + wv.y * c1.w + wv.z * c2.w + wv.w * c3.w;
  }
  __shared__ float redS[8], redQ[8];
#pragma unroll
  for (int f = 0; f < NF; ++f) {
    float s = t[f], q = t[f] * t[f];
#pragma unroll
    for (int o = 32; o > 0; o >>= 1) { s += __shfl_xor(s, o); q += __shfl_xor(q, o); }
    if (lane == 0) { redS[w] = s; redQ[w] = q; }
    __syncthreads();
    float S = 0.f, Q = 0.f;
#pragma unroll
    for (int j = 0; j < 8; ++j) { S += redS[j]; Q += redQ[j]; }
    float mu = S * (1.f / 512.f);
    float var = Q * (1.f / 512.f) - mu * mu;
    float rstd = rsqrtf(var + 1e-5f);
    float nv = (t[f] - mu) * rstd;
    cmq[f * DIN + i]  = nv * lnqg[i] + lnqb[i];
    cmp_[f * DIN + i] = nv * lnpg[i] + lnpb[i];
    __syncthreads();
  }
}

// ---------------- prep2: W->bf16 converts + xm = bf16(x*cmq) (separate launch: needs cmq) ----------------
__global__ void prep2_kernel(const float* __restrict__ W_qkv, const float* __restrict__ W_proj,
                             const float* __restrict__ x, const float* __restrict__ cmq,
                             unsigned short* __restrict__ Wqh, unsigned short* __restrict__ Wph,
                             unsigned short* __restrict__ xm) {
  const int bid = blockIdx.x, tid = threadIdx.x;
  if (bid < 256) {
    const float* src; unsigned short* dst; int e;
    if (bid < 192) { src = W_qkv; dst = Wqh; e = bid * 4096 + tid * 16; }
    else { src = W_proj; dst = Wph; e = (bid - 192) * 4096 + tid * 16; }
#pragma unroll
    for (int j = 0; j < 4; ++j) {
      float4 a = *reinterpret_cast<const float4*>(&src[e + j * 4]);
      us4 p = { f2b(a.x), f2b(a.y), f2b(a.z), f2b(a.w) };
      *reinterpret_cast<us4*>(&dst[e + j * 4]) = p;
    }
  } else {
    int e = (bid - 256) * 4096 + tid * 16;   // [4][1024][512] flat
    int row = e >> 9, d = e & 511;
    int f = row >> 10, n = row & 1023;
    const float* xr = x + (size_t)n * DIN + d;
    const float* cr = cmq + f * DIN + d;
#pragma unroll
    for (int j = 0; j < 4; ++j) {
      float4 a = *reinterpret_cast<const float4*>(xr + j * 4);
      float4 c = *reinterpret_cast<const float4*>(cr + j * 4);
      us4 p = { f2b(a.x * c.x), f2b(a.y * c.y), f2b(a.z * c.z), f2b(a.w * c.w) };
      *reinterpret_cast<us4*>(&xm[e + j * 4]) = p;
    }
  }
}

// ---------------- bf16 GEMM, 64x64 tile ----------------
template<int NCOL, bool OUT_BF16, bool WRITE_VT, bool SCALE_Q>
__global__ __launch_bounds__(256, 6)
void gemm64(const unsigned short* __restrict__ Ah,   // [4096][512]
            const unsigned short* __restrict__ Wh,   // [NCOL][512]
            const float* __restrict__ bias,
            unsigned short* __restrict__ outH,
            float* __restrict__ outF,
            unsigned short* __restrict__ vT) {
  __shared__ __align__(16) unsigned short sA[2][2048];
  __shared__ __align__(16) unsigned short sB[2][2048];
  const int tid = threadIdx.x;
  const int lane = tid & 63, w = tid >> 6;
  const int li = lane & 15, g = lane >> 4;
  const int wr = (w >> 1) * 32, wc = (w & 1) * 32;
  const int row0 = blockIdx.y * 64, col0 = blockIdx.x * 64;
  const int f = row0 >> 10;
  const int sr = tid >> 2, sp = tid & 3;
  const int ss = sp ^ ((sr >> 1) & 3);

  f32x4 acc[2][2];
#pragma unroll
  for (int m = 0; m < 2; ++m)
#pragma unroll
    for (int n = 0; n < 2; ++n) acc[m][n] = (f32x4){0.f, 0.f, 0.f, 0.f};

  const unsigned short* aSrc = Ah + (size_t)(row0 + sr) * DIN + ss * 8;
  const unsigned short* bSrc = Wh + (size_t)(col0 + sr) * DIN + ss * 8;

  gl_lds16(aSrc, &sA[0][w * 512]);
  gl_lds16(bSrc, &sB[0][w * 512]);
  __syncthreads();
  for (int it = 0; it < 16; ++it) {
    int buf = it & 1;
    if (it < 15) {
      gl_lds16(aSrc + (it + 1) * 32, &sA[buf ^ 1][w * 512]);
      gl_lds16(bSrc + (it + 1) * 32, &sB[buf ^ 1][w * 512]);
    }
    bf16x8 aF[2], bF[2];
#pragma unroll
    for (int m = 0; m < 2; ++m) {
      int ra = wr + m * 16 + li;
      aF[m] = *reinterpret_cast<const bf16x8*>(&sA[buf][(ra * 4 + (g ^ ((ra >> 1) & 3))) * 8]);
    }
#pragma unroll
    for (int n = 0; n < 2; ++n) {
      int cb = wc + n * 16 + li;
      bF[n] = *reinterpret_cast<const bf16x8*>(&sB[buf][(cb * 4 + (g ^ ((cb >> 1) & 3))) * 8]);
    }
#pragma unroll
    for (int m = 0; m < 2; ++m)
#pragma unroll
      for (int n = 0; n < 2; ++n)
        acc[m][n] = __builtin_amdgcn_mfma_f32_16x16x32_bf16(aF[m], bF[n], acc[m][n], 0, 0, 0);
    __syncthreads();
  }
#pragma unroll
  for (int n = 0; n < 2; ++n) {
    int col = col0 + wc + n * 16 + li;
    float bb = bias[col];
    float sc = (SCALE_Q && col < DIN) ? (0.125f * LOG2E) : 1.0f;
#pragma unroll
    for (int m = 0; m < 2; ++m) {
      int rb = row0 + wr + m * 16 + g * 4;
      f32x4 v = acc[m][n];
      if constexpr (OUT_BF16) {
        if (WRITE_VT && col >= 1024) {
          int tok0 = rb & 1023;
          us4 pk;
#pragma unroll
          for (int r = 0; r < 4; ++r) pk[r] = f2b(v[r] + bb);
          *reinterpret_cast<us4*>(&vT[((size_t)(f * 512 + (col - 1024))) * NTOK + tok0]) = pk;
        } else {
#pragma unroll
          for (int r = 0; r < 4; ++r)
            outH[(size_t)(rb + r) * NCOL + col] = f2b((v[r] + bb) * sc);
        }
      } else {
#pragma unroll
        for (int r = 0; r < 4; ++r)
          outF[(size_t)(rb + r) * NCOL + col] = v[r] + bb;
      }
    }
  }
}

// ---------------- MFMA attention v4: 8 waves, coop staging, <64KB LDS ----------------
__global__ __launch_bounds__(512, 4)
void attn_mfma4(const unsigned short* __restrict__ qkvh,  // [4][1024][1536] (Q scaled 0.125*log2e)
                const unsigned short* __restrict__ vTh,   // [4][512][1024] V^T
                const float* __restrict__ comp,           // [4][1024]
                const float* __restrict__ cmp_,           // [4][512]
                unsigned short* __restrict__ ym) {        // [4][1024][512] bf16*cmp_
  __shared__ __align__(16) unsigned short sK[2][4096];   // [ch] K tile (pass-A ping buf 0)
  __shared__ __align__(16) unsigned short sV[2][4096];   // [ch] V tile (pass-A ping buf 1)
  __shared__ __align__(16) unsigned short wbuf_all[8][16 * 68];
  __shared__ unsigned int sc01[1024], sc23[1024];
  __shared__ float lred[2][4][16];
  __shared__ float s2red[4][16];
  // total: 16384+16384+17408+8192+768 = 59136 B  (<64 KiB; 2 blocks/CU)

  const int tid = threadIdx.x, lane = tid & 63, w = tid >> 6;  // 8 waves
  const int li = lane & 15, g = lane >> 4;
  const int rt = w & 3, ch = w >> 2;
  const int hf = blockIdx.x, qt = blockIdx.y;
  const int h = hf >> 2, f = hf & 3;

  {
    int c = tid * 2;
    float2 a0 = *reinterpret_cast<const float2*>(&comp[c]);
    float2 a1 = *reinterpret_cast<const float2*>(&comp[1024 + c]);
    float2 a2 = *reinterpret_cast<const float2*>(&comp[2048 + c]);
    float2 a3 = *reinterpret_cast<const float2*>(&comp[3072 + c]);
    sc01[c]     = f2b(a0.x) | ((unsigned int)f2b(a1.x) << 16);
    sc01[c + 1] = f2b(a0.y) | ((unsigned int)f2b(a1.y) << 16);
    sc23[c]     = f2b(a2.x) | ((unsigned int)f2b(a3.x) << 16);
    sc23[c + 1] = f2b(a2.y) | ((unsigned int)f2b(a3.y) << 16);
  }

  const int qrow0 = qt * 64 + rt * 16;
  const unsigned short* qbase = qkvh + ((size_t)(f * NTOK + qrow0 + li)) * NQKV + h * HD;
  bf16x8 aq[2];
  aq[0] = *reinterpret_cast<const bf16x8*>(qbase + g * 8);
  aq[1] = *reinterpret_cast<const bf16x8*>(qbase + 32 + g * 8);

  float crow[4][4];
#pragma unroll
  for (int ff = 0; ff < 4; ++ff)
#pragma unroll
    for (int r = 0; r < 4; ++r)
      crow[ff][r] = comp[ff * NTOK + qrow0 + g * 4 + r];

  const unsigned short* kb = qkvh + ((size_t)(f * NTOK)) * NQKV + DIN + h * HD;
  const unsigned short* vb = vTh + ((size_t)(f * DIN + h * HD)) * NTOK;

  const int remK = w * 64 + lane;           // staging slot
  const int ktok = remK >> 3, kdg = remK & 7;
  const int ksw = kdg ^ (ktok & 7);

  auto stageK_to = [&](unsigned short (*dst)[4096], int s) {
#pragma unroll
    for (int j = 0; j < 2; ++j) {           // j = ch-half: tokens j*512 + s*64 ..
      int tokg = j * 512 + s * 64 + ktok;
      gl_lds16(kb + (size_t)tokg * NQKV + ksw * 8, &dst[j][(w * 64) * 8]);
    }
  };
  auto stageV_to = [&](int s) {
#pragma unroll
    for (int j = 0; j < 2; ++j) {
      int d = ktok, tg = kdg;
      int sw = tg ^ (d & 7);
      gl_lds16(vb + (size_t)d * NTOK + j * 512 + s * 64 + sw * 8, &sV[j][(w * 64) * 8]);
    }
  };

  // ---- pass A: lsum = sum(exp2(S')) over this wave's col half (ping-pong dbuf) ----
  float lsum[4] = {0.f, 0.f, 0.f, 0.f};
  stageK_to(sK, 0);
  __syncthreads();
  for (int s = 0; s < 8; ++s) {
    unsigned short (*cur)[4096] = (s & 1) ? sV : sK;
    if (s < 7) stageK_to((s & 1) ? sK : sV, s + 1);
    bf16x8 bk[4][2];
#pragma unroll
    for (int cf = 0; cf < 4; ++cf)
#pragma unroll
      for (int ks = 0; ks < 2; ++ks) {
        int tok = cf * 16 + li, dg = ks * 4 + g;
        bk[cf][ks] = *reinterpret_cast<const bf16x8*>(&cur[ch][(tok * 8 + (dg ^ (tok & 7))) * 8]);
      }
    f32x4 accs[4];
#pragma unroll
    for (int cf = 0; cf < 4; ++cf) accs[cf] = (f32x4){0.f, 0.f, 0.f, 0.f};
#pragma unroll
    for (int ks = 0; ks < 2; ++ks)
#pragma unroll
      for (int cf = 0; cf < 4; ++cf)
        accs[cf] = __builtin_amdgcn_mfma_f32_16x16x32_bf16(aq[ks], bk[cf][ks], accs[cf], 0, 0, 0);
#pragma unroll
    for (int cf = 0; cf < 4; ++cf)
#pragma unroll
      for (int r = 0; r < 4; ++r) lsum[r] += __builtin_amdgcn_exp2f(accs[cf][r]);
    __syncthreads();
  }
#pragma unroll
  for (int r = 0; r < 4; ++r) {
    lsum[r] += __shfl_xor(lsum[r], 1);
    lsum[r] += __shfl_xor(lsum[r], 2);
    lsum[r] += __shfl_xor(lsum[r], 4);
    lsum[r] += __shfl_xor(lsum[r], 8);
  }
  if (li == 0) {
#pragma unroll
    for (int r = 0; r < 4; ++r) lred[ch][rt][g * 4 + r] = lsum[r];
  }
  __syncthreads();
  float invl[4];
#pragma unroll
  for (int r = 0; r < 4; ++r)
    invl[r] = LOG2E / (lred[0][rt][g * 4 + r] + lred[1][rt][g * 4 + r]);

  // ---- pass B: t = exp2((exp2(S')*invl)*cc), PV + sum2 (stage-after-use) ----
  f32x4 acco[4];
  float sum2[4] = {0.f, 0.f, 0.f, 0.f};
#pragma unroll
  for (int cf = 0; cf < 4; ++cf) acco[cf] = (f32x4){0.f, 0.f, 0.f, 0.f};
  unsigned short* wb = wbuf_all[w];

  stageK_to(sK, 0);
  stageV_to(0);
  __syncthreads();
  for (int s = 0; s < 8; ++s) {
    bf16x8 bk[4][2];
#pragma unroll
    for (int cf = 0; cf < 4; ++cf)
#pragma unroll
      for (int ks = 0; ks < 2; ++ks) {
        int tok = cf * 16 + li, dg = ks * 4 + g;
        bk[cf][ks] = *reinterpret_cast<const bf16x8*>(&sK[ch][(tok * 8 + (dg ^ (tok & 7))) * 8]);
      }
    f32x4 accs[4];
#pragma unroll
    for (int cf = 0; cf < 4; ++cf) accs[cf] = (f32x4){0.f, 0.f, 0.f, 0.f};
#pragma unroll
    for (int ks = 0; ks < 2; ++ks)
#pragma unroll
      for (int cf = 0; cf < 4; ++cf)
        accs[cf] = __builtin_amdgcn_mfma_f32_16x16x32_bf16(aq[ks], bk[cf][ks], accs[cf], 0, 0, 0);
#pragma unroll
    for (int cf = 0; cf < 4; ++cf) {
      int colg = ch * 512 + s * 64 + cf * 16 + li;
      unsigned int u01 = sc01[colg], u23 = sc23[colg];
      float c0 = asf(u01 << 16), c1 = asf(u01 & 0xffff0000u);
      float c2 = asf(u23 << 16), c3 = asf(u23 & 0xffff0000u);
#pragma unroll
      for (int r = 0; r < 4; ++r) {
        float e = __builtin_amdgcn_exp2f(accs[cf][r]);
        float a = e * invl[r];
        float cc = crow[0][r] * c0 + crow[1][r] * c1 + crow[2][r] * c2 + crow[3][r] * c3;
        float tv = __builtin_amdgcn_exp2f(a * cc);
        unsigned short hv = f2b(tv);
        sum2[r] += b2f(hv);
        wb[(g * 4 + r) * 68 + cf * 16 + li] = hv;
      }
    }
    bf16x8 aw[2], bv[4][2];
#pragma unroll
    for (int ks = 0; ks < 2; ++ks)
      aw[ks] = *reinterpret_cast<const bf16x8*>(&wb[li * 68 + ks * 32 + g * 8]);
#pragma unroll
    for (int cf = 0; cf < 4; ++cf)
#pragma unroll
      for (int ks = 0; ks < 2; ++ks) {
        int d = cf * 16 + li, tg = ks * 4 + g;
        bv[cf][ks] = *reinterpret_cast<const bf16x8*>(&sV[ch][(d * 8 + (tg ^ (d & 7))) * 8]);
      }
#pragma unroll
    for (int ks = 0; ks < 2; ++ks)
#pragma unroll
      for (int cf = 0; cf < 4; ++cf)
        acco[cf] = __builtin_amdgcn_mfma_f32_16x16x32_bf16(aw[ks], bv[cf][ks], acco[cf], 0, 0, 0);
    __syncthreads();            // all reads of sK/sV for tile s done
    if (s < 7) { stageK_to(sK, s + 1); stageV_to(s + 1); }
    __syncthreads();            // staged tile s+1 visible (vmcnt drained at barrier)
  }

  // ---- combine across ch, write ym ----
#pragma unroll
  for (int r = 0; r < 4; ++r) {
    sum2[r] += __shfl_xor(sum2[r], 1);
    sum2[r] += __shfl_xor(sum2[r], 2);
    sum2[r] += __shfl_xor(sum2[r], 4);
    sum2[r] += __shfl_xor(sum2[r], 8);
  }
  float* fred = (float*)sK;  // 16 KB reuse (sK no longer needed)
  __syncthreads();
  if (ch == 1) {
    if (li == 0) {
#pragma unroll
      for (int r = 0; r < 4; ++r) s2red[rt][g * 4 + r] = sum2[r];
    }
#pragma unroll
    for (int cf = 0; cf < 4; ++cf)
#pragma unroll
      for (int r = 0; r < 4; ++r)
        fred[rt * 1024 + (g * 4 + r) * 64 + cf * 16 + li] = acco[cf][r];
  }
  __syncthreads();
  if (ch == 0) {
    float invs[4];
#pragma unroll
    for (int r = 0; r < 4; ++r) invs[r] = 1.f / (sum2[r] + s2red[rt][g * 4 + r]);
    float cscale[4];
#pragma unroll
    for (int cf = 0; cf < 4; ++cf) cscale[cf] = cmp_[f * DIN + h * HD + cf * 16 + li];
#pragma unroll
    for (int cf = 0; cf < 4; ++cf)
#pragma unroll
      for (int r = 0; r < 4; ++r) {
        float v = (acco[cf][r] + fred[rt * 1024 + (g * 4 + r) * 64 + cf * 16 + li]) * invs[r];
        int qrow = qrow0 + g * 4 + r;
        ym[((size_t)(f * NTOK + qrow)) * DIN + h * HD + cf * 16 + li] = f2b(v * cscale[cf]);
      }
  }
}

extern "C" void kernel_launch(void* const* d_in, const int* in_sizes, int n_in,
                              void* d_out, int out_size, void* d_ws, size_t ws_size,
                              hipStream_t stream) {
  const float* x      = (const float*)d_in[0];
  const float* compat = (const float*)d_in[1];
  const float* code   = (const float*)d_in[2];
  const float* w_c    = (const float*)d_in[3];
  const float* W_qkv  = (const float*)d_in[4];
  const float* b_qkv  = (const float*)d_in[5];
  const float* W_proj = (const float*)d_in[6];
  const float* b_proj = (const float*)d_in[7];
  const float* lnqg   = (const float*)d_in[8];
  const float* lnqb   = (const float*)d_in[9];
  const float* lnpg   = (const float*)d_in[10];
  const float* lnpb   = (const float*)d_in[11];
  float* out = (float*)d_out;

  float* cmq  = (float*)d_ws;
  float* cmp_ = cmq + NF * DIN;
  unsigned short* Wqh  = (unsigned short*)(cmp_ + NF * DIN);
  unsigned short* Wph  = Wqh + (size_t)NQKV * DIN;
  unsigned short* xm   = Wph + (size_t)DIN * DIN;
  unsigned short* qkvh = xm + (size_t)NF * NTOK * DIN;
  unsigned short* vTh  = qkvh + (size_t)NF * NTOK * NQKV;
  unsigned short* ym   = vTh + (size_t)NF * DIN * NTOK;

  ln_kernel<<<1, 512, 0, stream>>>(code, w_c, lnqg, lnqb, lnpg, lnpb, cmq, cmp_);
  prep2_kernel<<<768, 256, 0, stream>>>(W_qkv, W_proj, x, cmq, Wqh, Wph, xm);
  gemm64<NQKV, true, true, true><<<dim3(24, 64), 256, 0, stream>>>(
      xm, Wqh, b_qkv, qkvh, nullptr, vTh);
  attn_mfma4<<<dim3(32, 16), 512, 0, stream>>>(qkvh, vTh, compat, cmp_, ym);
  gemm64<DIN, false, false, false><<<dim3(8, 64), 256, 0, stream>>>(
      ym, Wph, b_proj, nullptr, out, nullptr);
}